// Round 2
// baseline (18267.119 us; speedup 1.0000x reference)
//
#include <hip/hip_runtime.h>
#include <hip/hip_cooperative_groups.h>
#include <stdint.h>

namespace cg = cooperative_groups;

typedef uint32_t u32;
typedef __bf16 bf16;
typedef bf16 bf16x8 __attribute__((ext_vector_type(8)));
typedef float f32x4 __attribute__((ext_vector_type(4)));

#define B_ 256
#define T_ 256
#define H_ 1024
#define G_ 4096   // 4*H
#define NI_ 2048

// ---- workspace layout ----
static constexpr size_t OFF_W2T = 0;                           // [2][4096 grouped cols][1024 k] bf16
static constexpr size_t SZ_W2T  = (size_t)2 * G_ * H_ * 2;     // 16 MB
static constexpr size_t OFF_H   = OFF_W2T + SZ_W2T;            // [2 pp][2 dir][B][H] bf16
static constexpr size_t SZ_H    = (size_t)2 * 2 * B_ * H_ * 2; // 2 MB
static constexpr size_t OFF_RL  = OFF_H + SZ_H;                // 256 f32

// ---- LDS layout (dynamic, 133376 B) ----
static constexpr int LDS_W    = 0;         // 64 vcols x 1024 k bf16, XOR-swizzled = 131072 B
static constexpr int LDS_XA   = 131072;    // 3 acts x 64 vcols f32 = 768 B (Wt[2048+a] + bias)
static constexpr int LDS_ITEM = 131840;    // 128 int
static constexpr int LDS_ACT  = 132352;    // 128 int
static constexpr int LDS_LEN  = 132864;    // 128 int
static constexpr int LDS_TOTAL= 133376;

__device__ __forceinline__ float bf2f(uint16_t b){ return __uint_as_float(((u32)b) << 16); }
__device__ __forceinline__ uint16_t f2bf(float f){
  u32 u = __float_as_uint(f);
  return (uint16_t)((u + 0x7fffu + ((u >> 16) & 1u)) >> 16);  // RNE
}
__device__ __forceinline__ float sigm(float x){ return 1.f / (1.f + __expf(-x)); }
__device__ __forceinline__ float tanh_(float x){ return 1.f - 2.f / (__expf(2.f * x) + 1.f); }

// threefry2x32, jax rotations
__device__ __forceinline__ void threefry(u32 k0, u32 k1, u32 x0, u32 x1, u32& o0, u32& o1){
  u32 ks2 = k0 ^ k1 ^ 0x1BD11BDAu;
  x0 += k0; x1 += k1;
#define TFR(r) { x0 += x1; x1 = (x1 << r) | (x1 >> (32 - r)); x1 ^= x0; }
  TFR(13) TFR(15) TFR(26) TFR(6)  x0 += k1;  x1 += ks2 + 1u;
  TFR(17) TFR(29) TFR(16) TFR(24) x0 += ks2; x1 += k0 + 2u;
  TFR(13) TFR(15) TFR(26) TFR(6)  x0 += k0;  x1 += k1 + 3u;
  TFR(17) TFR(29) TFR(16) TFR(24) x0 += k1;  x1 += ks2 + 4u;
  TFR(13) TFR(15) TFR(26) TFR(6)  x0 += ks2; x1 += k0 + 5u;
#undef TFR
  o0 = x0; o1 = x1;
}

__device__ __forceinline__ bool keep_mask(u32 idx){
  u32 o0, o1; threefry(0u, 42u, 0u, idx, o0, o1);
  return ((o0 ^ o1) & 0x80000000u) == 0u;
}

// ---- prep: Whh (1024, 4096) f32 -> w2t[d][vcg][k] bf16
// col = strip*1024 + hcol, hcol = n*16 + c  ->  vcg = n*64 + strip*16 + c
__global__ __launch_bounds__(256) void k_prep_w(const float* __restrict__ whh_f,
                                                const float* __restrict__ whh_b,
                                                uint16_t* __restrict__ w2t){
  int bid = blockIdx.x;
  int d  = bid >> 12;
  int r  = bid & 4095;
  int kt = r >> 7;           // 32 k-tiles of 32
  int ct = r & 127;          // 128 col-tiles of 32
  const float* W = d ? whh_b : whh_f;
  __shared__ float tile[32][33];
  int tid = threadIdx.x;
  int lr = tid >> 5, lc = tid & 31;
#pragma unroll
  for (int i = 0; i < 4; i++)
    tile[lr + i*8][lc] = W[(size_t)(kt*32 + lr + i*8) * G_ + ct*32 + lc];
  __syncthreads();
  int colLocal = tid >> 3, kseg = tid & 7;
  int col = ct*32 + colLocal;
  int strip = col >> 10;
  int hcol  = col & 1023;
  int vcg = (hcol >> 4)*64 + strip*16 + (hcol & 15);
  size_t base = ((size_t)d * G_ + vcg) * H_ + kt*32 + kseg*4;
  u32 w0 = (u32)f2bf(tile[kseg*4+0][colLocal]) | ((u32)f2bf(tile[kseg*4+1][colLocal]) << 16);
  u32 w1 = (u32)f2bf(tile[kseg*4+2][colLocal]) | ((u32)f2bf(tile[kseg*4+3][colLocal]) << 16);
  uint2 v; v.x = w0; v.y = w1;
  *(uint2*)(w2t + base) = v;
}

// ---- persistent bidirectional LSTM. 256 blocks x 256 threads, cooperative.
// block: d = bid>>7, m = (bid>>6)&1 (128 rows), n = bid&63 (16 hcols -> 64 gate cols)
__global__ __launch_bounds__(256, 1) void k_persist(
    const int* __restrict__ items, const int* __restrict__ actions,
    const float* __restrict__ wt_f, const float* __restrict__ wt_b,
    const float* __restrict__ bias_f, const float* __restrict__ bias_b,
    const uint16_t* __restrict__ w2t, uint16_t* __restrict__ hbuf)
{
  cg::grid_group grid = cg::this_grid();
  extern __shared__ char smem[];
  uint16_t* wlds = (uint16_t*)(smem + LDS_W);
  float*    xa   = (float*)   (smem + LDS_XA);
  int*      s_item = (int*)   (smem + LDS_ITEM);
  int*      s_act  = (int*)   (smem + LDS_ACT);
  int*      s_len  = (int*)   (smem + LDS_LEN);

  int bid = blockIdx.x;
  int d = bid >> 7;
  int m = (bid >> 6) & 1;
  int n = bid & 63;
  int tid = threadIdx.x;
  int b0 = m * 128;
  int ncol = n * 16;
  const float* wt   = d ? wt_b : wt_f;
  const float* bias = d ? bias_b : bias_f;

  // --- load W slice to LDS (XOR-swizzled along k) ---
  {
    const char* wsrc = (const char*)(w2t + ((size_t)d * G_ + n*64) * H_);
#pragma unroll
    for (int i = 0; i < 32; i++){
      int u = i*256 + tid;              // 8192 x 16B
      int row = u >> 7, seg = u & 127;
      int sb = seg * 16;
      uint4 v = *(const uint4*)(wsrc + row*2048 + sb);
      *(uint4*)(smem + LDS_W + row*2048 + (sb ^ ((row & 7) << 4))) = v;
    }
  }
  // --- xa[a][vcol] = Wt[2048+a][gcol] + bias[gcol], a in {0,1,2} ---
  if (tid < 192){
    int a = tid >> 6, vcol = tid & 63;
    int gcol = (vcol >> 4)*1024 + ncol + (vcol & 15);
    xa[tid] = wt[(size_t)(2*NI_/2 + NI_ + a - NI_) * 0 + (size_t)(NI_ + a) * G_ + gcol] + bias[gcol];
  }
  // --- lens for this block's rows ---
  if (tid < 128){
    int b = b0 + tid, cnt = 0;
    for (int t = 0; t < T_; t++) cnt += (items[(size_t)b * T_ + t] != 0) ? 1 : 0;
    s_len[tid] = cnt;
  }
  // --- zero this block's slice of h buffer 0 ---
  {
    uint16_t* hz = hbuf + (size_t)d * B_ * H_;
#pragma unroll
    for (int i = 0; i < 8; i++){
      int u = i*256 + tid;              // 2048 = 128 rows x 16 cols
      int row = u >> 4, cc = u & 15;
      hz[(size_t)(b0 + row) * H_ + ncol + cc] = 0;
    }
  }
  __syncthreads();
  __threadfence();
  grid.sync();

  // per-lane constants
  int w = tid >> 6;          // wave 0..3, rows w*32..w*32+31
  int l = tid & 63;
  int c = l & 15;            // hidden-col within group; also MFMA frag col
  int lk = l >> 4;           // k-segment 0..3
  int key = (c & 7) << 4;    // LDS XOR swizzle key
  int klo = lk * 16;

  float c_reg[8];
  uint16_t h_reg[8];
#pragma unroll
  for (int i = 0; i < 8; i++){ c_reg[i] = 0.f; h_reg[i] = 0; }

  for (int s = 0; s < T_; s++){
    int t = d ? (T_ - 1 - s) : s;
    if (tid < 128){
      s_item[tid] = items[(size_t)(b0 + tid) * T_ + t];
      s_act[tid]  = actions[(size_t)(b0 + tid) * T_ + t];
    }
    __syncthreads();

    // --- init acc with x = Wt[item] + (Wt[2048+act] + bias) ---
    f32x4 acc[2][4];
#pragma unroll
    for (int mi = 0; mi < 2; mi++)
#pragma unroll
      for (int r4 = 0; r4 < 4; r4++){
        int rowl = w*32 + mi*16 + lk*4 + r4;
        int item = s_item[rowl];
        int act  = s_act[rowl];
#pragma unroll
        for (int strip = 0; strip < 4; strip++){
          float x = wt[(size_t)item * G_ + strip*1024 + ncol + c]
                  + xa[act*64 + strip*16 + c];
          acc[mi][strip][r4] = x;
        }
      }

    // --- K loop: A from global (h), B from LDS (weights) ---
    const uint16_t* hin  = hbuf + ((size_t)((s & 1)*2 + d)) * B_ * H_;
    uint16_t*       hout = hbuf + ((size_t)(((s & 1) ^ 1)*2 + d)) * B_ * H_;
    const uint16_t* ha0 = hin + (size_t)(b0 + w*32 + c) * H_ + lk*8;
    const uint16_t* ha1 = ha0 + 16 * H_;
    bf16x8 p0[2], p1[2];
    p0[0] = *(const bf16x8*)(ha0);       p1[0] = *(const bf16x8*)(ha1);
    p0[1] = *(const bf16x8*)(ha0 + 32);  p1[1] = *(const bf16x8*)(ha1 + 32);
#pragma unroll
    for (int kk = 0; kk < 32; kk++){
      bf16x8 a0 = p0[kk & 1], a1 = p1[kk & 1];
      if (kk < 30){
        p0[kk & 1] = *(const bf16x8*)(ha0 + (kk + 2)*32);
        p1[kk & 1] = *(const bf16x8*)(ha1 + (kk + 2)*32);
      }
      int kb = kk * 64;
#pragma unroll
      for (int strip = 0; strip < 4; strip++){
        int off = LDS_W + (strip*16 + c)*2048 + (((kb | klo)) ^ key);
        bf16x8 bb = *(const bf16x8*)(smem + off);
        acc[0][strip] = __builtin_amdgcn_mfma_f32_16x16x32_bf16(a0, bb, acc[0][strip], 0, 0, 0);
        acc[1][strip] = __builtin_amdgcn_mfma_f32_16x16x32_bf16(a1, bb, acc[1][strip], 0, 0, 0);
      }
    }

    // --- epilogue: gates in-register, c in regs, store h ---
#pragma unroll
    for (int mi = 0; mi < 2; mi++)
#pragma unroll
      for (int r4 = 0; r4 < 4; r4++){
        int rowl = w*32 + mi*16 + lk*4 + r4;
        int i8 = mi*4 + r4;
        if (t < s_len[rowl]){
          float i_ = sigm(acc[mi][0][r4]);
          float f_ = sigm(acc[mi][1][r4]);
          float g_ = tanh_(acc[mi][2][r4]);
          float o_ = sigm(acc[mi][3][r4]);
          float cn = f_ * c_reg[i8] + i_ * g_;
          c_reg[i8] = cn;
          h_reg[i8] = f2bf(o_ * tanh_(cn));
        }
        hout[(size_t)(b0 + rowl) * H_ + ncol + c] = h_reg[i8];
      }
    __threadfence();
    grid.sync();
  }
}

// ---- FC + per-row loss ----
__global__ __launch_bounds__(256) void k_fc(const uint16_t* __restrict__ hfin,
    const float* __restrict__ wfc, const float* __restrict__ bfc,
    const int* __restrict__ targets, float* __restrict__ rowloss){
  int b = blockIdx.x, tid = threadIdx.x;
  float a0 = 0.f, a1 = 0.f;
  for (int jj = tid; jj < 2*H_; jj += 256){
    int d = jj >> 10, j = jj & 1023;
    float h = bf2f(hfin[(size_t)d * B_ * H_ + (size_t)b * H_ + j]);
    u32 idx = (u32)(d * (B_ * H_) + b * H_ + j);
    float feat = keep_mask(idx) ? (2.f * h) : 0.f;
    a0 += feat * wfc[jj*2 + 0];
    a1 += feat * wfc[jj*2 + 1];
  }
#pragma unroll
  for (int off = 32; off > 0; off >>= 1){
    a0 += __shfl_down(a0, off, 64);
    a1 += __shfl_down(a1, off, 64);
  }
  __shared__ float r0[4], r1[4];
  if ((tid & 63) == 0){ r0[tid >> 6] = a0; r1[tid >> 6] = a1; }
  __syncthreads();
  if (tid == 0){
    float l0 = r0[0]+r0[1]+r0[2]+r0[3] + bfc[0];
    float l1 = r1[0]+r1[1]+r1[2]+r1[3] + bfc[1];
    float mx = fmaxf(l0, l1);
    float lse = mx + logf(__expf(l0 - mx) + __expf(l1 - mx));
    rowloss[b] = lse - (targets[b] ? l1 : l0);
  }
}

__global__ __launch_bounds__(256) void k_loss(const float* __restrict__ rowloss, float* __restrict__ out){
  int tid = threadIdx.x;
  float v = rowloss[tid];
#pragma unroll
  for (int off = 32; off > 0; off >>= 1) v += __shfl_down(v, off, 64);
  __shared__ float r[4];
  if ((tid & 63) == 0) r[tid >> 6] = v;
  __syncthreads();
  if (tid == 0) out[0] = (r[0] + r[1] + r[2] + r[3]) * (1.f / B_);
}

extern "C" void kernel_launch(void* const* d_in, const int* in_sizes, int n_in,
                              void* d_out, int out_size, void* d_ws, size_t ws_size,
                              hipStream_t stream){
  (void)in_sizes; (void)n_in; (void)out_size; (void)ws_size;
  const int*   items   = (const int*)  d_in[0];
  const int*   actions = (const int*)  d_in[1];
  const int*   targets = (const int*)  d_in[2];
  const float* wt_f    = (const float*)d_in[3];
  const float* whh_f   = (const float*)d_in[4];
  const float* b_f     = (const float*)d_in[5];
  const float* wt_b    = (const float*)d_in[6];
  const float* whh_b   = (const float*)d_in[7];
  const float* b_b     = (const float*)d_in[8];
  const float* wfc     = (const float*)d_in[9];
  const float* bfc     = (const float*)d_in[10];

  char* ws = (char*)d_ws;
  uint16_t* w2t   = (uint16_t*)(ws + OFF_W2T);
  uint16_t* hbuf  = (uint16_t*)(ws + OFF_H);
  float*    rlbuf = (float*)   (ws + OFF_RL);

  hipFuncSetAttribute((const void*)k_persist,
                      hipFuncAttributeMaxDynamicSharedMemorySize, LDS_TOTAL);

  hipLaunchKernelGGL(k_prep_w, dim3(8192), dim3(256), 0, stream, whh_f, whh_b, w2t);

  void* args[] = { (void*)&items, (void*)&actions, (void*)&wt_f, (void*)&wt_b,
                   (void*)&b_f, (void*)&b_b, (void*)&w2t, (void*)&hbuf };
  hipLaunchCooperativeKernel((const void*)k_persist, dim3(256), dim3(256),
                             args, LDS_TOTAL, stream);

  hipLaunchKernelGGL(k_fc,   dim3(256), dim3(256), 0, stream, hbuf, wfc, bfc, targets, rlbuf);
  hipLaunchKernelGGL(k_loss, dim3(1),   dim3(256), 0, stream, rlbuf, (float*)d_out);
}

// Round 3
// 4444.564 us; speedup vs baseline: 4.1100x; 4.1100x over previous
//
#include <hip/hip_runtime.h>
#include <stdint.h>

typedef uint32_t u32;
typedef __bf16 bf16;
typedef bf16 bf16x8 __attribute__((ext_vector_type(8)));
typedef float f32x4 __attribute__((ext_vector_type(4)));

#define B_ 256
#define T_ 256
#define H_ 1024
#define G_ 4096   // 4*H
#define NI_ 2048

// ---- workspace layout ----
static constexpr size_t OFF_W2T = 0;                           // [2][4096 grouped cols][1024 k] bf16
static constexpr size_t SZ_W2T  = (size_t)2 * G_ * H_ * 2;     // 16 MB
static constexpr size_t OFF_H   = OFF_W2T + SZ_W2T;            // [2 pp][2 dir][B][H] bf16
static constexpr size_t SZ_H    = (size_t)2 * 2 * B_ * H_ * 2; // 2 MB
static constexpr size_t OFF_LENS= OFF_H + SZ_H;                // 256 i32
static constexpr size_t OFF_RL  = OFF_LENS + 1024;             // 256 f32
static constexpr size_t OFF_BAR = OFF_RL + 1024;               // barrier counters
static constexpr size_t SZ_BAR  = 36864 * 4;                   // 144 KB (arr 2048x16 u32 + fin 256x16 u32)

static constexpr int LDS_BYTES = 131072;                       // 64 vcols x 1024 k bf16, swizzled

__device__ __forceinline__ float bf2f(uint16_t b){ return __uint_as_float(((u32)b) << 16); }
__device__ __forceinline__ uint16_t f2bf(float f){
  u32 u = __float_as_uint(f);
  return (uint16_t)((u + 0x7fffu + ((u >> 16) & 1u)) >> 16);  // RNE
}
__device__ __forceinline__ float sigm(float x){ return 1.f / (1.f + __expf(-x)); }
__device__ __forceinline__ float tanh_(float x){ return 1.f - 2.f / (__expf(2.f * x) + 1.f); }

// threefry2x32, jax rotations
__device__ __forceinline__ void threefry(u32 k0, u32 k1, u32 x0, u32 x1, u32& o0, u32& o1){
  u32 ks2 = k0 ^ k1 ^ 0x1BD11BDAu;
  x0 += k0; x1 += k1;
#define TFR(r) { x0 += x1; x1 = (x1 << r) | (x1 >> (32 - r)); x1 ^= x0; }
  TFR(13) TFR(15) TFR(26) TFR(6)  x0 += k1;  x1 += ks2 + 1u;
  TFR(17) TFR(29) TFR(16) TFR(24) x0 += ks2; x1 += k0 + 2u;
  TFR(13) TFR(15) TFR(26) TFR(6)  x0 += k0;  x1 += k1 + 3u;
  TFR(17) TFR(29) TFR(16) TFR(24) x0 += k1;  x1 += ks2 + 4u;
  TFR(13) TFR(15) TFR(26) TFR(6)  x0 += ks2; x1 += k0 + 5u;
#undef TFR
  o0 = x0; o1 = x1;
}

__device__ __forceinline__ bool keep_mask(u32 idx){
  u32 o0, o1; threefry(0u, 42u, 0u, idx, o0, o1);
  return ((o0 ^ o1) & 0x80000000u) == 0u;
}

// ---- prep: Whh (1024, 4096) f32 -> w2t[d][vcg][k] bf16
// col = strip*1024 + hcol, hcol = n*16 + c  ->  vcg = n*64 + strip*16 + c
__global__ __launch_bounds__(256) void k_prep_w(const float* __restrict__ whh_f,
                                                const float* __restrict__ whh_b,
                                                uint16_t* __restrict__ w2t){
  int bid = blockIdx.x;
  int d  = bid >> 12;
  int r  = bid & 4095;
  int kt = r >> 7;           // 32 k-tiles of 32
  int ct = r & 127;          // 128 col-tiles of 32
  const float* W = d ? whh_b : whh_f;
  __shared__ float tile[32][33];
  int tid = threadIdx.x;
  int lr = tid >> 5, lc = tid & 31;
#pragma unroll
  for (int i = 0; i < 4; i++)
    tile[lr + i*8][lc] = W[(size_t)(kt*32 + lr + i*8) * G_ + ct*32 + lc];
  __syncthreads();
  int colLocal = tid >> 3, kseg = tid & 7;
  int col = ct*32 + colLocal;
  int strip = col >> 10;
  int hcol  = col & 1023;
  int vcg = (hcol >> 4)*64 + strip*16 + (hcol & 15);
  size_t base = ((size_t)d * G_ + vcg) * H_ + kt*32 + kseg*4;
  u32 w0 = (u32)f2bf(tile[kseg*4+0][colLocal]) | ((u32)f2bf(tile[kseg*4+1][colLocal]) << 16);
  u32 w1 = (u32)f2bf(tile[kseg*4+2][colLocal]) | ((u32)f2bf(tile[kseg*4+3][colLocal]) << 16);
  uint2 v; v.x = w0; v.y = w1;
  *(uint2*)(w2t + base) = v;
}

// ---- init: zero h(pp=0) + barrier counters; block 256 computes lens
__global__ __launch_bounds__(256) void k_init(uint16_t* __restrict__ hbuf,
                                              int* __restrict__ lens,
                                              u32* __restrict__ bar,
                                              const int* __restrict__ items){
  int bid = blockIdx.x, tid = threadIdx.x;
  if (bid == 256){
    int cnt = 0;
    for (int t = 0; t < T_; t++) cnt += (items[(size_t)tid * T_ + t] != 0) ? 1 : 0;
    lens[tid] = cnt;
    return;
  }
  size_t g = (size_t)bid * 256 + tid;                 // 65536 threads x 16B = 1MB (pp0, both dirs)
  ((uint4*)hbuf)[g] = make_uint4(0,0,0,0);
  if (tid < 36)
    ((uint4*)bar)[bid*36 + tid] = make_uint4(0,0,0,0);  // 9216 uint4 = 144KB
}

// ---- asm helpers: agent-coherent (MALL-level) h access + counted waits ----
#define A_LOAD(dst, base, IMM) \
  asm volatile("global_load_dwordx4 %0, %1, off offset:%2 sc0 sc1" \
    : "=v"(dst) : "v"(base), "i"(IMM) : "memory")
#define A_WAIT(N, r0, r1) \
  asm volatile("s_waitcnt vmcnt(%2)" : "+v"(r0), "+v"(r1) : "i"(N) : "memory")
#define AISS(j) { A_LOAD(pre0[(j)&15], p0, (j)*64); A_LOAD(pre1[(j)&15], p1, (j)*64); }

#define KS1(kk,st,bb) { \
  acc0[st] = __builtin_amdgcn_mfma_f32_16x16x32_bf16(a0_, bb, acc0[st], 0,0,0); \
  acc1[st] = __builtin_amdgcn_mfma_f32_16x16x32_bf16(a1_, bb, acc1[st], 0,0,0); }

#define KSTEP(kk) { \
  bf16x8 bb0 = *(const bf16x8*)(smem + qoff00 + (((kk)&1)?qd1:qd0) + (((kk)&30)<<6)); \
  bf16x8 bb1 = *(const bf16x8*)(smem + qoff00 + 32768  + (((kk)&1)?qd1:qd0) + (((kk)&30)<<6)); \
  bf16x8 bb2 = *(const bf16x8*)(smem + qoff00 + 65536  + (((kk)&1)?qd1:qd0) + (((kk)&30)<<6)); \
  bf16x8 bb3 = *(const bf16x8*)(smem + qoff00 + 98304  + (((kk)&1)?qd1:qd0) + (((kk)&30)<<6)); \
  A_WAIT(((kk)<=16 ? 30 : 62-2*(kk)), pre0[(kk)&15], pre1[(kk)&15]); \
  bf16x8 a0_ = pre0[(kk)&15]; bf16x8 a1_ = pre1[(kk)&15]; \
  KS1(kk,0,bb0) KS1(kk,1,bb1) KS1(kk,2,bb2) KS1(kk,3,bb3) \
  if ((kk) < 16) { AISS((kk)+16); } }

#define R4(M,a) M(a) M((a)+1) M((a)+2) M((a)+3)
#define R16(M,a) R4(M,a) R4(M,(a)+4) R4(M,(a)+8) R4(M,(a)+12)

// ---- persistent bidirectional LSTM. 256 blocks x 256 threads, cooperative launch,
// custom lightweight barrier (no L2 invalidation).
__global__ __launch_bounds__(256, 1) void k_persist(
    const int* __restrict__ items, const int* __restrict__ actions,
    const float* __restrict__ wt_f, const float* __restrict__ wt_b,
    const float* __restrict__ bias_f, const float* __restrict__ bias_b,
    const uint16_t* __restrict__ w2t, uint16_t* __restrict__ hbuf,
    const int* __restrict__ lens, u32* __restrict__ bar)
{
  extern __shared__ char smem[];
  const int bid = blockIdx.x;
  const int d = bid >> 7;
  const int m = (bid >> 6) & 1;
  const int n = bid & 63;
  const int tid = threadIdx.x;
  const int b0 = m * 128;
  const int ncol = n * 16;
  const float* wt   = d ? wt_b : wt_f;
  const float* bias = d ? bias_b : bias_f;

  // --- W slice -> LDS, XOR-swizzled along k ---
  {
    const char* wsrc = (const char*)(w2t + ((size_t)d * G_ + n*64) * H_);
#pragma unroll
    for (int i = 0; i < 32; i++){
      int u = i*256 + tid;              // 8192 x 16B = 128KB
      int row = u >> 7, seg = u & 127;
      int sb = seg * 16;
      uint4 v = *(const uint4*)(wsrc + row*2048 + sb);
      *(uint4*)(smem + row*2048 + (sb ^ ((row & 7) << 4))) = v;
    }
  }

  const int w  = tid >> 6;   // wave 0..3, rows w*32..w*32+31
  const int l  = tid & 63;
  const int c  = l & 15;     // frag col = hidden col offset
  const int lk = l >> 4;     // k-seg
  const int gc = ncol + c;

  // --- per-lane constants ---
  float xav[3][4];
#pragma unroll
  for (int a = 0; a < 3; a++)
#pragma unroll
    for (int st = 0; st < 4; st++)
      xav[a][st] = wt[(size_t)(NI_ + a) * G_ + st*1024 + gc] + bias[st*1024 + gc];

  int len_r[8];
#pragma unroll
  for (int i = 0; i < 8; i++)
    len_r[i] = lens[b0 + w*32 + (i>>2)*16 + lk*4 + (i&3)];

  int it_c[8], ac_c[8];
  const int t0 = d ? (T_-1) : 0;
#pragma unroll
  for (int i = 0; i < 8; i++){
    int row = b0 + w*32 + (i>>2)*16 + lk*4 + (i&3);
    it_c[i] = items[(size_t)row * T_ + t0];
    ac_c[i] = actions[(size_t)row * T_ + t0];
  }

  // LDS b-read offset pieces: off = (st*16+c)*2048 + ((kk*64 + lk*16) ^ ((c&7)<<4))
  const int key  = (c & 7) << 4;
  const int kbit = (c >> 2) & 1;
  const u32 qoff00 = (u32)(c*2048 + ((lk*16) ^ (key & 48)));
  const u32 qd0 = (u32)((kbit) << 6);
  const u32 qd1 = (u32)((1 ^ kbit) << 6);

  float c_reg[8]; uint16_t h_reg[8];
#pragma unroll
  for (int i = 0; i < 8; i++){ c_reg[i] = 0.f; h_reg[i] = 0; }

  __syncthreads();   // W LDS ready (block-local)

  bf16x8 pre0[16], pre1[16];

  for (int s = 0; s < T_; s++){
    const int t = d ? (T_-1-s) : s;

    // --- acc init: x = Wt[item] + (Wt[NI+act] + bias), f32 gather (normal cached loads) ---
    f32x4 acc0[4], acc1[4];
#pragma unroll
    for (int r4 = 0; r4 < 4; r4++){
      const float* w0r = wt + (size_t)it_c[r4]   * G_ + gc;
      const float* w1r = wt + (size_t)it_c[4+r4] * G_ + gc;
#pragma unroll
      for (int st = 0; st < 4; st++){
        acc0[st][r4] = w0r[st*1024] + xav[ac_c[r4]][st];
        acc1[st][r4] = w1r[st*1024] + xav[ac_c[4+r4]][st];
      }
    }
    __builtin_amdgcn_sched_barrier(0);   // keep compiler vmem + its waits above the asm pipeline

    const uint16_t* hin  = hbuf + ((size_t)((s&1)*2 + d)) * B_ * H_;
    uint16_t*       hout = hbuf + ((size_t)(((s&1)^1)*2 + d)) * B_ * H_;
    const char* p0 = (const char*)hin + (size_t)(b0 + w*32 + c)*2048 + lk*16;
    const char* p1 = p0 + 16*2048;

    // --- prologue: issue 16 pairs of coherent A loads ---
    R16(AISS, 0)
    // --- k-loop: 32 fully-unrolled iterations ---
    R16(KSTEP, 0)
    R16(KSTEP, 16)
    __builtin_amdgcn_sched_barrier(0);

    // --- epilogue: gates in registers, c in registers, coherent h stores ---
    int tn = d ? (t > 0 ? t-1 : 0) : (t < T_-1 ? t+1 : t);
#pragma unroll
    for (int mi = 0; mi < 2; mi++)
#pragma unroll
      for (int r4 = 0; r4 < 4; r4++){
        int i8 = mi*4 + r4;
        int row = b0 + w*32 + mi*16 + lk*4 + r4;
        float g0 = mi ? acc1[0][r4] : acc0[0][r4];
        float g1 = mi ? acc1[1][r4] : acc0[1][r4];
        float g2 = mi ? acc1[2][r4] : acc0[2][r4];
        float g3 = mi ? acc1[3][r4] : acc0[3][r4];
        if (t < len_r[i8]){
          float i_ = sigm(g0);
          float f_ = sigm(g1);
          float gg = tanh_(g2);
          float o_ = sigm(g3);
          float cn = f_ * c_reg[i8] + i_ * gg;
          c_reg[i8] = cn;
          h_reg[i8] = f2bf(o_ * tanh_(cn));
        }
        const uint16_t* addr = hout + (size_t)row * H_ + gc;
        u32 hv = h_reg[i8];
        asm volatile("global_store_short %0, %1, off sc0 sc1" :: "v"(addr), "v"(hv) : "memory");
      }
    asm volatile("s_waitcnt vmcnt(0)" ::: "memory");
    __syncthreads();
    if (s == T_-1) break;

    // --- lightweight global barrier: release-adds (writeback, no invalidate) + relaxed polls ---
    u32* arr = bar + ((u32)s*8 + (u32)(bid & 7))*16;
    u32* fin = bar + 32768 + (u32)s*16;
    if (tid == 0){
      u32 old = __hip_atomic_fetch_add(arr, 1u, __ATOMIC_RELEASE, __HIP_MEMORY_SCOPE_AGENT);
      if (old == 31u)
        __hip_atomic_fetch_add(fin, 1u, __ATOMIC_RELEASE, __HIP_MEMORY_SCOPE_AGENT);
    }
    // prefetch next step's item/action while waiting
#pragma unroll
    for (int i = 0; i < 8; i++){
      int row = b0 + w*32 + (i>>2)*16 + lk*4 + (i&3);
      it_c[i] = items[(size_t)row * T_ + tn];
      ac_c[i] = actions[(size_t)row * T_ + tn];
    }
    if (tid == 0){
      while (__hip_atomic_load(fin, __ATOMIC_RELAXED, __HIP_MEMORY_SCOPE_AGENT) < 8u)
        __builtin_amdgcn_s_sleep(2);
    }
    __syncthreads();
  }
}

// ---- FC + per-row loss ----
__global__ __launch_bounds__(256) void k_fc(const uint16_t* __restrict__ hfin,
    const float* __restrict__ wfc, const float* __restrict__ bfc,
    const int* __restrict__ targets, float* __restrict__ rowloss){
  int b = blockIdx.x, tid = threadIdx.x;
  float a0 = 0.f, a1 = 0.f;
  for (int jj = tid; jj < 2*H_; jj += 256){
    int d = jj >> 10, j = jj & 1023;
    float h = bf2f(hfin[(size_t)d * B_ * H_ + (size_t)b * H_ + j]);
    u32 idx = (u32)(d * (B_ * H_) + b * H_ + j);
    float feat = keep_mask(idx) ? (2.f * h) : 0.f;
    a0 += feat * wfc[jj*2 + 0];
    a1 += feat * wfc[jj*2 + 1];
  }
#pragma unroll
  for (int off = 32; off > 0; off >>= 1){
    a0 += __shfl_down(a0, off, 64);
    a1 += __shfl_down(a1, off, 64);
  }
  __shared__ float r0[4], r1[4];
  if ((tid & 63) == 0){ r0[tid >> 6] = a0; r1[tid >> 6] = a1; }
  __syncthreads();
  if (tid == 0){
    float l0 = r0[0]+r0[1]+r0[2]+r0[3] + bfc[0];
    float l1 = r1[0]+r1[1]+r1[2]+r1[3] + bfc[1];
    float mx = fmaxf(l0, l1);
    float lse = mx + logf(__expf(l0 - mx) + __expf(l1 - mx));
    rowloss[b] = lse - (targets[b] ? l1 : l0);
  }
}

__global__ __launch_bounds__(256) void k_loss(const float* __restrict__ rowloss, float* __restrict__ out){
  int tid = threadIdx.x;
  float v = rowloss[tid];
#pragma unroll
  for (int off = 32; off > 0; off >>= 1) v += __shfl_down(v, off, 64);
  __shared__ float r[4];
  if ((tid & 63) == 0) r[tid >> 6] = v;
  __syncthreads();
  if (tid == 0) out[0] = (r[0] + r[1] + r[2] + r[3]) * (1.f / B_);
}

extern "C" void kernel_launch(void* const* d_in, const int* in_sizes, int n_in,
                              void* d_out, int out_size, void* d_ws, size_t ws_size,
                              hipStream_t stream){
  (void)in_sizes; (void)n_in; (void)out_size; (void)ws_size;
  const int*   items   = (const int*)  d_in[0];
  const int*   actions = (const int*)  d_in[1];
  const int*   targets = (const int*)  d_in[2];
  const float* wt_f    = (const float*)d_in[3];
  const float* whh_f   = (const float*)d_in[4];
  const float* b_f     = (const float*)d_in[5];
  const float* wt_b    = (const float*)d_in[6];
  const float* whh_b   = (const float*)d_in[7];
  const float* b_b     = (const float*)d_in[8];
  const float* wfc     = (const float*)d_in[9];
  const float* bfc     = (const float*)d_in[10];

  char* ws = (char*)d_ws;
  uint16_t* w2t   = (uint16_t*)(ws + OFF_W2T);
  uint16_t* hbuf  = (uint16_t*)(ws + OFF_H);
  int*      lens  = (int*)     (ws + OFF_LENS);
  float*    rlbuf = (float*)   (ws + OFF_RL);
  u32*      bar   = (u32*)     (ws + OFF_BAR);

  hipFuncSetAttribute((const void*)k_persist,
                      hipFuncAttributeMaxDynamicSharedMemorySize, LDS_BYTES);

  hipLaunchKernelGGL(k_prep_w, dim3(8192), dim3(256), 0, stream, whh_f, whh_b, w2t);
  hipLaunchKernelGGL(k_init,   dim3(257),  dim3(256), 0, stream, hbuf, lens, bar, items);

  void* args[] = { (void*)&items, (void*)&actions, (void*)&wt_f, (void*)&wt_b,
                   (void*)&b_f, (void*)&b_b, (void*)&w2t, (void*)&hbuf,
                   (void*)&lens, (void*)&bar };
  hipLaunchCooperativeKernel((const void*)k_persist, dim3(256), dim3(256),
                             args, LDS_BYTES, stream);

  hipLaunchKernelGGL(k_fc,   dim3(256), dim3(256), 0, stream, hbuf, wfc, bfc, targets, rlbuf);
  hipLaunchKernelGGL(k_loss, dim3(1),   dim3(256), 0, stream, rlbuf, (float*)d_out);
}

// Round 4
// 4443.800 us; speedup vs baseline: 4.1107x; 1.0002x over previous
//
#include <hip/hip_runtime.h>
#include <stdint.h>

typedef uint32_t u32;
typedef __bf16 bf16;
typedef bf16 bf16x8 __attribute__((ext_vector_type(8)));
typedef float f32x4 __attribute__((ext_vector_type(4)));

#define B_ 256
#define T_ 256
#define H_ 1024
#define G_ 4096   // 4*H
#define NI_ 2048

// ---- workspace layout ----
static constexpr size_t OFF_W2T = 0;                           // [2][4096 grouped cols][1024 k] bf16
static constexpr size_t SZ_W2T  = (size_t)2 * G_ * H_ * 2;     // 16 MB
static constexpr size_t OFF_H   = OFF_W2T + SZ_W2T;            // [2 pp][2 dir][B][H] bf16
static constexpr size_t SZ_H    = (size_t)2 * 2 * B_ * H_ * 2; // 2 MB
static constexpr size_t OFF_LENS= OFF_H + SZ_H;                // 256 i32
static constexpr size_t OFF_RL  = OFF_LENS + 1024;             // 256 f32
static constexpr size_t OFF_BAR = OFF_RL + 1024;               // barrier counters
static constexpr size_t SZ_BAR  = 36864 * 4;                   // 144 KB (arr 2048x16 u32 + fin 256x16 u32)

static constexpr int LDS_BYTES = 131072;                       // 64 vcols x 1024 k bf16, swizzled

__device__ __forceinline__ float bf2f(uint16_t b){ return __uint_as_float(((u32)b) << 16); }
__device__ __forceinline__ uint16_t f2bf(float f){
  u32 u = __float_as_uint(f);
  return (uint16_t)((u + 0x7fffu + ((u >> 16) & 1u)) >> 16);  // RNE
}
__device__ __forceinline__ float sigm(float x){ return 1.f / (1.f + __expf(-x)); }
__device__ __forceinline__ float tanh_(float x){ return 1.f - 2.f / (__expf(2.f * x) + 1.f); }

// threefry2x32, jax rotations
__device__ __forceinline__ void threefry(u32 k0, u32 k1, u32 x0, u32 x1, u32& o0, u32& o1){
  u32 ks2 = k0 ^ k1 ^ 0x1BD11BDAu;
  x0 += k0; x1 += k1;
#define TFR(r) { x0 += x1; x1 = (x1 << r) | (x1 >> (32 - r)); x1 ^= x0; }
  TFR(13) TFR(15) TFR(26) TFR(6)  x0 += k1;  x1 += ks2 + 1u;
  TFR(17) TFR(29) TFR(16) TFR(24) x0 += ks2; x1 += k0 + 2u;
  TFR(13) TFR(15) TFR(26) TFR(6)  x0 += k0;  x1 += k1 + 3u;
  TFR(17) TFR(29) TFR(16) TFR(24) x0 += k1;  x1 += ks2 + 4u;
  TFR(13) TFR(15) TFR(26) TFR(6)  x0 += ks2; x1 += k0 + 5u;
#undef TFR
  o0 = x0; o1 = x1;
}

__device__ __forceinline__ bool keep_mask(u32 idx){
  u32 o0, o1; threefry(0u, 42u, 0u, idx, o0, o1);
  return ((o0 ^ o1) & 0x80000000u) == 0u;
}

// ---- prep: Whh (1024, 4096) f32 -> w2t[d][vcg][k] bf16
// col = strip*1024 + hcol, hcol = n*16 + c  ->  vcg = n*64 + strip*16 + c
__global__ __launch_bounds__(256) void k_prep_w(const float* __restrict__ whh_f,
                                                const float* __restrict__ whh_b,
                                                uint16_t* __restrict__ w2t){
  int bid = blockIdx.x;
  int d  = bid >> 12;
  int r  = bid & 4095;
  int kt = r >> 7;           // 32 k-tiles of 32
  int ct = r & 127;          // 128 col-tiles of 32
  const float* W = d ? whh_b : whh_f;
  __shared__ float tile[32][33];
  int tid = threadIdx.x;
  int lr = tid >> 5, lc = tid & 31;
#pragma unroll
  for (int i = 0; i < 4; i++)
    tile[lr + i*8][lc] = W[(size_t)(kt*32 + lr + i*8) * G_ + ct*32 + lc];
  __syncthreads();
  int colLocal = tid >> 3, kseg = tid & 7;
  int col = ct*32 + colLocal;
  int strip = col >> 10;
  int hcol  = col & 1023;
  int vcg = (hcol >> 4)*64 + strip*16 + (hcol & 15);
  size_t base = ((size_t)d * G_ + vcg) * H_ + kt*32 + kseg*4;
  u32 w0 = (u32)f2bf(tile[kseg*4+0][colLocal]) | ((u32)f2bf(tile[kseg*4+1][colLocal]) << 16);
  u32 w1 = (u32)f2bf(tile[kseg*4+2][colLocal]) | ((u32)f2bf(tile[kseg*4+3][colLocal]) << 16);
  uint2 v; v.x = w0; v.y = w1;
  *(uint2*)(w2t + base) = v;
}

// ---- init: zero h(pp=0) + barrier counters; block 256 computes lens
__global__ __launch_bounds__(256) void k_init(uint16_t* __restrict__ hbuf,
                                              int* __restrict__ lens,
                                              u32* __restrict__ bar,
                                              const int* __restrict__ items){
  int bid = blockIdx.x, tid = threadIdx.x;
  if (bid == 256){
    int cnt = 0;
    for (int t = 0; t < T_; t++) cnt += (items[(size_t)tid * T_ + t] != 0) ? 1 : 0;
    lens[tid] = cnt;
    return;
  }
  size_t g = (size_t)bid * 256 + tid;                 // 65536 threads x 16B = 1MB (pp0, both dirs)
  ((uint4*)hbuf)[g] = make_uint4(0,0,0,0);
  if (tid < 36)
    ((uint4*)bar)[bid*36 + tid] = make_uint4(0,0,0,0);  // 9216 uint4 = 144KB
}

// ---- asm helpers: agent-coherent (MALL-level) h access + counted waits ----
#define A_LOAD(dst, base, IMM) \
  asm volatile("global_load_dwordx4 %0, %1, off offset:%2 sc0 sc1" \
    : "=v"(dst) : "v"(base), "i"(IMM) : "memory")
#define A_WAIT(N, r0, r1) \
  asm volatile("s_waitcnt vmcnt(%2)" : "+v"(r0), "+v"(r1) : "i"(N) : "memory")
#define AISS(j) { A_LOAD(pre0[(j)&15], p0, (j)*64); A_LOAD(pre1[(j)&15], p1, (j)*64); }

#define KS1(kk,st,bb) { \
  acc0[st] = __builtin_amdgcn_mfma_f32_16x16x32_bf16(a0_, bb, acc0[st], 0,0,0); \
  acc1[st] = __builtin_amdgcn_mfma_f32_16x16x32_bf16(a1_, bb, acc1[st], 0,0,0); }

#define KSTEP(kk) { \
  bf16x8 bb0 = *(const bf16x8*)(smem + qoff00 + (((kk)&1)?qd1:qd0) + (((kk)&30)<<6)); \
  bf16x8 bb1 = *(const bf16x8*)(smem + qoff00 + 32768  + (((kk)&1)?qd1:qd0) + (((kk)&30)<<6)); \
  bf16x8 bb2 = *(const bf16x8*)(smem + qoff00 + 65536  + (((kk)&1)?qd1:qd0) + (((kk)&30)<<6)); \
  bf16x8 bb3 = *(const bf16x8*)(smem + qoff00 + 98304  + (((kk)&1)?qd1:qd0) + (((kk)&30)<<6)); \
  A_WAIT(((kk)<=16 ? 30 : 62-2*(kk)), pre0[(kk)&15], pre1[(kk)&15]); \
  bf16x8 a0_ = pre0[(kk)&15]; bf16x8 a1_ = pre1[(kk)&15]; \
  KS1(kk,0,bb0) KS1(kk,1,bb1) KS1(kk,2,bb2) KS1(kk,3,bb3) \
  if ((kk) < 16) { AISS((kk)+16); } }

#define R4(M,a) M(a) M((a)+1) M((a)+2) M((a)+3)
#define R16(M,a) R4(M,a) R4(M,(a)+4) R4(M,(a)+8) R4(M,(a)+12)

// ---- persistent bidirectional LSTM. 256 blocks x 256 threads, cooperative launch,
// custom lightweight barrier (no L2 invalidation).
__global__ __launch_bounds__(256, 1) void k_persist(
    const int* __restrict__ items, const int* __restrict__ actions,
    const float* __restrict__ wt_f, const float* __restrict__ wt_b,
    const float* __restrict__ bias_f, const float* __restrict__ bias_b,
    const uint16_t* __restrict__ w2t, uint16_t* __restrict__ hbuf,
    const int* __restrict__ lens, u32* __restrict__ bar)
{
  extern __shared__ char smem[];
  const int bid = blockIdx.x;
  const int d = bid >> 7;
  const int m = (bid >> 6) & 1;
  const int n = bid & 63;
  const int tid = threadIdx.x;
  const int b0 = m * 128;
  const int ncol = n * 16;
  const float* wt   = d ? wt_b : wt_f;
  const float* bias = d ? bias_b : bias_f;

  // --- W slice -> LDS, XOR-swizzled along k ---
  {
    const char* wsrc = (const char*)(w2t + ((size_t)d * G_ + n*64) * H_);
#pragma unroll
    for (int i = 0; i < 32; i++){
      int u = i*256 + tid;              // 8192 x 16B = 128KB
      int row = u >> 7, seg = u & 127;
      int sb = seg * 16;
      uint4 v = *(const uint4*)(wsrc + row*2048 + sb);
      *(uint4*)(smem + row*2048 + (sb ^ ((row & 7) << 4))) = v;
    }
  }

  const int w  = tid >> 6;   // wave 0..3, rows w*32..w*32+31
  const int l  = tid & 63;
  const int c  = l & 15;     // frag col = hidden col offset
  const int lk = l >> 4;     // k-seg
  const int gc = ncol + c;

  // --- per-lane constants ---
  float xav[3][4];
#pragma unroll
  for (int a = 0; a < 3; a++)
#pragma unroll
    for (int st = 0; st < 4; st++)
      xav[a][st] = wt[(size_t)(NI_ + a) * G_ + st*1024 + gc] + bias[st*1024 + gc];

  int len_r[8];
#pragma unroll
  for (int i = 0; i < 8; i++)
    len_r[i] = lens[b0 + w*32 + (i>>2)*16 + lk*4 + (i&3)];

  int it_c[8], ac_c[8];
  const int t0 = d ? (T_-1) : 0;
#pragma unroll
  for (int i = 0; i < 8; i++){
    int row = b0 + w*32 + (i>>2)*16 + lk*4 + (i&3);
    it_c[i] = items[(size_t)row * T_ + t0];
    ac_c[i] = actions[(size_t)row * T_ + t0];
  }

  // LDS b-read offset pieces: off = (st*16+c)*2048 + ((kk*64 + lk*16) ^ ((c&7)<<4))
  const int key  = (c & 7) << 4;
  const int kbit = (c >> 2) & 1;
  const u32 qoff00 = (u32)(c*2048 + ((lk*16) ^ (key & 48)));
  const u32 qd0 = (u32)((kbit) << 6);
  const u32 qd1 = (u32)((1 ^ kbit) << 6);

  float c_reg[8]; uint16_t h_reg[8];
#pragma unroll
  for (int i = 0; i < 8; i++){ c_reg[i] = 0.f; h_reg[i] = 0; }

  __syncthreads();   // W LDS ready (block-local)

  bf16x8 pre0[16], pre1[16];

  for (int s = 0; s < T_; s++){
    const int t = d ? (T_-1-s) : s;

    // --- acc init: x = Wt[item] + (Wt[NI+act] + bias), f32 gather (normal cached loads) ---
    f32x4 acc0[4], acc1[4];
#pragma unroll
    for (int r4 = 0; r4 < 4; r4++){
      const float* w0r = wt + (size_t)it_c[r4]   * G_ + gc;
      const float* w1r = wt + (size_t)it_c[4+r4] * G_ + gc;
#pragma unroll
      for (int st = 0; st < 4; st++){
        acc0[st][r4] = w0r[st*1024] + xav[ac_c[r4]][st];
        acc1[st][r4] = w1r[st*1024] + xav[ac_c[4+r4]][st];
      }
    }
    __builtin_amdgcn_sched_barrier(0);   // keep compiler vmem + its waits above the asm pipeline

    const uint16_t* hin  = hbuf + ((size_t)((s&1)*2 + d)) * B_ * H_;
    uint16_t*       hout = hbuf + ((size_t)(((s&1)^1)*2 + d)) * B_ * H_;
    const char* p0 = (const char*)hin + (size_t)(b0 + w*32 + c)*2048 + lk*16;
    const char* p1 = p0 + 16*2048;

    // --- prologue: issue 16 pairs of coherent A loads ---
    R16(AISS, 0)
    // --- k-loop: 32 fully-unrolled iterations ---
    R16(KSTEP, 0)
    R16(KSTEP, 16)
    __builtin_amdgcn_sched_barrier(0);

    // --- epilogue: gates in registers, c in registers, coherent h stores ---
    int tn = d ? (t > 0 ? t-1 : 0) : (t < T_-1 ? t+1 : t);
#pragma unroll
    for (int mi = 0; mi < 2; mi++)
#pragma unroll
      for (int r4 = 0; r4 < 4; r4++){
        int i8 = mi*4 + r4;
        int row = b0 + w*32 + mi*16 + lk*4 + r4;
        float g0 = mi ? acc1[0][r4] : acc0[0][r4];
        float g1 = mi ? acc1[1][r4] : acc0[1][r4];
        float g2 = mi ? acc1[2][r4] : acc0[2][r4];
        float g3 = mi ? acc1[3][r4] : acc0[3][r4];
        if (t < len_r[i8]){
          float i_ = sigm(g0);
          float f_ = sigm(g1);
          float gg = tanh_(g2);
          float o_ = sigm(g3);
          float cn = f_ * c_reg[i8] + i_ * gg;
          c_reg[i8] = cn;
          h_reg[i8] = f2bf(o_ * tanh_(cn));
        }
        const uint16_t* addr = hout + (size_t)row * H_ + gc;
        u32 hv = h_reg[i8];
        asm volatile("global_store_short %0, %1, off sc0 sc1" :: "v"(addr), "v"(hv) : "memory");
      }
    asm volatile("s_waitcnt vmcnt(0)" ::: "memory");
    __syncthreads();
    if (s == T_-1) break;

    // --- lightweight global barrier: release-adds (writeback, no invalidate) + relaxed polls ---
    u32* arr = bar + ((u32)s*8 + (u32)(bid & 7))*16;
    u32* fin = bar + 32768 + (u32)s*16;
    if (tid == 0){
      u32 old = __hip_atomic_fetch_add(arr, 1u, __ATOMIC_RELEASE, __HIP_MEMORY_SCOPE_AGENT);
      if (old == 31u)
        __hip_atomic_fetch_add(fin, 1u, __ATOMIC_RELEASE, __HIP_MEMORY_SCOPE_AGENT);
    }
    // prefetch next step's item/action while waiting
#pragma unroll
    for (int i = 0; i < 8; i++){
      int row = b0 + w*32 + (i>>2)*16 + lk*4 + (i&3);
      it_c[i] = items[(size_t)row * T_ + tn];
      ac_c[i] = actions[(size_t)row * T_ + tn];
    }
    if (tid == 0){
      while (__hip_atomic_load(fin, __ATOMIC_RELAXED, __HIP_MEMORY_SCOPE_AGENT) < 8u)
        __builtin_amdgcn_s_sleep(2);
    }
    __syncthreads();
  }
}

// ---- FC + per-row loss ----
__global__ __launch_bounds__(256) void k_fc(const uint16_t* __restrict__ hfin,
    const float* __restrict__ wfc, const float* __restrict__ bfc,
    const int* __restrict__ targets, float* __restrict__ rowloss){
  int b = blockIdx.x, tid = threadIdx.x;
  float a0 = 0.f, a1 = 0.f;
  for (int jj = tid; jj < 2*H_; jj += 256){
    int d = jj >> 10, j = jj & 1023;
    float h = bf2f(hfin[(size_t)d * B_ * H_ + (size_t)b * H_ + j]);
    u32 idx = (u32)(d * (B_ * H_) + b * H_ + j);
    float feat = keep_mask(idx) ? (2.f * h) : 0.f;
    a0 += feat * wfc[jj*2 + 0];
    a1 += feat * wfc[jj*2 + 1];
  }
#pragma unroll
  for (int off = 32; off > 0; off >>= 1){
    a0 += __shfl_down(a0, off, 64);
    a1 += __shfl_down(a1, off, 64);
  }
  __shared__ float r0[4], r1[4];
  if ((tid & 63) == 0){ r0[tid >> 6] = a0; r1[tid >> 6] = a1; }
  __syncthreads();
  if (tid == 0){
    float l0 = r0[0]+r0[1]+r0[2]+r0[3] + bfc[0];
    float l1 = r1[0]+r1[1]+r1[2]+r1[3] + bfc[1];
    float mx = fmaxf(l0, l1);
    float lse = mx + logf(__expf(l0 - mx) + __expf(l1 - mx));
    rowloss[b] = lse - (targets[b] ? l1 : l0);
  }
}

__global__ __launch_bounds__(256) void k_loss(const float* __restrict__ rowloss, float* __restrict__ out){
  int tid = threadIdx.x;
  float v = rowloss[tid];
#pragma unroll
  for (int off = 32; off > 0; off >>= 1) v += __shfl_down(v, off, 64);
  __shared__ float r[4];
  if ((tid & 63) == 0) r[tid >> 6] = v;
  __syncthreads();
  if (tid == 0) out[0] = (r[0] + r[1] + r[2] + r[3]) * (1.f / B_);
}

extern "C" void kernel_launch(void* const* d_in, const int* in_sizes, int n_in,
                              void* d_out, int out_size, void* d_ws, size_t ws_size,
                              hipStream_t stream){
  (void)in_sizes; (void)n_in; (void)out_size; (void)ws_size;
  const int*   items   = (const int*)  d_in[0];
  const int*   actions = (const int*)  d_in[1];
  const int*   targets = (const int*)  d_in[2];
  const float* wt_f    = (const float*)d_in[3];
  const float* whh_f   = (const float*)d_in[4];
  const float* b_f     = (const float*)d_in[5];
  const float* wt_b    = (const float*)d_in[6];
  const float* whh_b   = (const float*)d_in[7];
  const float* b_b     = (const float*)d_in[8];
  const float* wfc     = (const float*)d_in[9];
  const float* bfc     = (const float*)d_in[10];

  char* ws = (char*)d_ws;
  uint16_t* w2t   = (uint16_t*)(ws + OFF_W2T);
  uint16_t* hbuf  = (uint16_t*)(ws + OFF_H);
  int*      lens  = (int*)     (ws + OFF_LENS);
  float*    rlbuf = (float*)   (ws + OFF_RL);
  u32*      bar   = (u32*)     (ws + OFF_BAR);

  hipFuncSetAttribute((const void*)k_persist,
                      hipFuncAttributeMaxDynamicSharedMemorySize, LDS_BYTES);

  hipLaunchKernelGGL(k_prep_w, dim3(8192), dim3(256), 0, stream, whh_f, whh_b, w2t);
  hipLaunchKernelGGL(k_init,   dim3(257),  dim3(256), 0, stream, hbuf, lens, bar, items);

  void* args[] = { (void*)&items, (void*)&actions, (void*)&wt_f, (void*)&wt_b,
                   (void*)&b_f, (void*)&b_b, (void*)&w2t, (void*)&hbuf,
                   (void*)&lens, (void*)&bar };
  hipLaunchCooperativeKernel((const void*)k_persist, dim3(256), dim3(256),
                             args, LDS_BYTES, stream);

  hipLaunchKernelGGL(k_fc,   dim3(256), dim3(256), 0, stream, hbuf, wfc, bfc, targets, rlbuf);
  hipLaunchKernelGGL(k_loss, dim3(1),   dim3(256), 0, stream, rlbuf, (float*)d_out);
}

// Round 5
// 4440.279 us; speedup vs baseline: 4.1140x; 1.0008x over previous
//
#include <hip/hip_runtime.h>
#include <stdint.h>

typedef uint32_t u32;
typedef __bf16 bf16;
typedef bf16 bf16x8 __attribute__((ext_vector_type(8)));
typedef float f32x4 __attribute__((ext_vector_type(4)));

#define B_ 256
#define T_ 256
#define H_ 1024
#define G_ 4096   // 4*H
#define NI_ 2048

// ---- workspace layout ----
static constexpr size_t OFF_W2T = 0;                           // [2][4096 grouped cols][1024 k] bf16
static constexpr size_t SZ_W2T  = (size_t)2 * G_ * H_ * 2;     // 16 MB
static constexpr size_t OFF_H   = OFF_W2T + SZ_W2T;            // [2 pp][2 dir][B][H] bf16
static constexpr size_t SZ_H    = (size_t)2 * 2 * B_ * H_ * 2; // 2 MB
static constexpr size_t OFF_LENS= OFF_H + SZ_H;                // 256 i32
static constexpr size_t OFF_RL  = OFF_LENS + 1024;             // 256 f32
static constexpr size_t OFF_BAR = OFF_RL + 1024;               // barrier counters
static constexpr size_t SZ_BAR  = 36864 * 4;                   // 144 KB (arr 2048x16 u32 + fin 256x16 u32)

static constexpr int LDS_BYTES = 131072;                       // 64 vcols x 1024 k bf16, swizzled

__device__ __forceinline__ float bf2f(uint16_t b){ return __uint_as_float(((u32)b) << 16); }
__device__ __forceinline__ uint16_t f2bf(float f){
  u32 u = __float_as_uint(f);
  return (uint16_t)((u + 0x7fffu + ((u >> 16) & 1u)) >> 16);  // RNE
}
__device__ __forceinline__ float sigm(float x){ return 1.f / (1.f + __expf(-x)); }
__device__ __forceinline__ float tanh_(float x){ return 1.f - 2.f / (__expf(2.f * x) + 1.f); }

// threefry2x32, jax rotations
__device__ __forceinline__ void threefry(u32 k0, u32 k1, u32 x0, u32 x1, u32& o0, u32& o1){
  u32 ks2 = k0 ^ k1 ^ 0x1BD11BDAu;
  x0 += k0; x1 += k1;
#define TFR(r) { x0 += x1; x1 = (x1 << r) | (x1 >> (32 - r)); x1 ^= x0; }
  TFR(13) TFR(15) TFR(26) TFR(6)  x0 += k1;  x1 += ks2 + 1u;
  TFR(17) TFR(29) TFR(16) TFR(24) x0 += ks2; x1 += k0 + 2u;
  TFR(13) TFR(15) TFR(26) TFR(6)  x0 += k0;  x1 += k1 + 3u;
  TFR(17) TFR(29) TFR(16) TFR(24) x0 += k1;  x1 += ks2 + 4u;
  TFR(13) TFR(15) TFR(26) TFR(6)  x0 += ks2; x1 += k0 + 5u;
#undef TFR
  o0 = x0; o1 = x1;
}

__device__ __forceinline__ bool keep_mask(u32 idx){
  u32 o0, o1; threefry(0u, 42u, 0u, idx, o0, o1);
  return ((o0 ^ o1) & 0x80000000u) == 0u;
}

// ---- prep: Whh (1024, 4096) f32 -> w2t[d][vcg][k] bf16
// col = strip*1024 + hcol, hcol = n*16 + c  ->  vcg = n*64 + strip*16 + c
__global__ __launch_bounds__(256) void k_prep_w(const float* __restrict__ whh_f,
                                                const float* __restrict__ whh_b,
                                                uint16_t* __restrict__ w2t){
  int bid = blockIdx.x;
  int d  = bid >> 12;
  int r  = bid & 4095;
  int kt = r >> 7;           // 32 k-tiles of 32
  int ct = r & 127;          // 128 col-tiles of 32
  const float* W = d ? whh_b : whh_f;
  __shared__ float tile[32][33];
  int tid = threadIdx.x;
  int lr = tid >> 5, lc = tid & 31;
#pragma unroll
  for (int i = 0; i < 4; i++)
    tile[lr + i*8][lc] = W[(size_t)(kt*32 + lr + i*8) * G_ + ct*32 + lc];
  __syncthreads();
  int colLocal = tid >> 3, kseg = tid & 7;
  int col = ct*32 + colLocal;
  int strip = col >> 10;
  int hcol  = col & 1023;
  int vcg = (hcol >> 4)*64 + strip*16 + (hcol & 15);
  size_t base = ((size_t)d * G_ + vcg) * H_ + kt*32 + kseg*4;
  u32 w0 = (u32)f2bf(tile[kseg*4+0][colLocal]) | ((u32)f2bf(tile[kseg*4+1][colLocal]) << 16);
  u32 w1 = (u32)f2bf(tile[kseg*4+2][colLocal]) | ((u32)f2bf(tile[kseg*4+3][colLocal]) << 16);
  uint2 v; v.x = w0; v.y = w1;
  *(uint2*)(w2t + base) = v;
}

// ---- init: zero h(pp=0) + barrier counters; block 256 computes lens
__global__ __launch_bounds__(256) void k_init(uint16_t* __restrict__ hbuf,
                                              int* __restrict__ lens,
                                              u32* __restrict__ bar,
                                              const int* __restrict__ items){
  int bid = blockIdx.x, tid = threadIdx.x;
  if (bid == 256){
    int cnt = 0;
    for (int t = 0; t < T_; t++) cnt += (items[(size_t)tid * T_ + t] != 0) ? 1 : 0;
    lens[tid] = cnt;
    return;
  }
  size_t g = (size_t)bid * 256 + tid;                 // 65536 threads x 16B = 1MB (pp0, both dirs)
  ((uint4*)hbuf)[g] = make_uint4(0,0,0,0);
  if (tid < 36)
    ((uint4*)bar)[bid*36 + tid] = make_uint4(0,0,0,0);  // 9216 uint4 = 144KB
}

// ---- asm helpers: agent-coherent (MALL-level) h access + counted waits ----
#define A_LOAD(dst, base, IMM) \
  asm volatile("global_load_dwordx4 %0, %1, off offset:%2 sc0 sc1" \
    : "=v"(dst) : "v"(base), "i"(IMM) : "memory")
#define A_WAIT(N, r0, r1) \
  asm volatile("s_waitcnt vmcnt(%2)" : "+v"(r0), "+v"(r1) : "i"(N) : "memory")
#define AISS(j) { A_LOAD(pre0[(j)&15], p0, (j)*64); A_LOAD(pre1[(j)&15], p1, (j)*64); }

#define KS1(kk,st,bb) { \
  acc0[st] = __builtin_amdgcn_mfma_f32_16x16x32_bf16(a0_, bb, acc0[st], 0,0,0); \
  acc1[st] = __builtin_amdgcn_mfma_f32_16x16x32_bf16(a1_, bb, acc1[st], 0,0,0); }

#define KSTEP(kk) { \
  bf16x8 bb0 = *(const bf16x8*)(smem + qoff00 + (((kk)&1)?qd1:qd0) + (((kk)&30)<<6)); \
  bf16x8 bb1 = *(const bf16x8*)(smem + qoff00 + 32768  + (((kk)&1)?qd1:qd0) + (((kk)&30)<<6)); \
  bf16x8 bb2 = *(const bf16x8*)(smem + qoff00 + 65536  + (((kk)&1)?qd1:qd0) + (((kk)&30)<<6)); \
  bf16x8 bb3 = *(const bf16x8*)(smem + qoff00 + 98304  + (((kk)&1)?qd1:qd0) + (((kk)&30)<<6)); \
  A_WAIT(((kk)<=16 ? 30 : 62-2*(kk)), pre0[(kk)&15], pre1[(kk)&15]); \
  bf16x8 a0_ = pre0[(kk)&15]; bf16x8 a1_ = pre1[(kk)&15]; \
  KS1(kk,0,bb0) KS1(kk,1,bb1) KS1(kk,2,bb2) KS1(kk,3,bb3) \
  if ((kk) < 16) { AISS((kk)+16); } }

#define R4(M,a) M(a) M((a)+1) M((a)+2) M((a)+3)
#define R16(M,a) R4(M,a) R4(M,(a)+4) R4(M,(a)+8) R4(M,(a)+12)

// ---- persistent bidirectional LSTM. 256 blocks x 256 threads, cooperative launch,
// custom lightweight barrier (no L2 invalidation).
__global__ __launch_bounds__(256, 1) void k_persist(
    const int* __restrict__ items, const int* __restrict__ actions,
    const float* __restrict__ wt_f, const float* __restrict__ wt_b,
    const float* __restrict__ bias_f, const float* __restrict__ bias_b,
    const uint16_t* __restrict__ w2t, uint16_t* __restrict__ hbuf,
    const int* __restrict__ lens, u32* __restrict__ bar)
{
  extern __shared__ char smem[];
  const int bid = blockIdx.x;
  const int d = bid >> 7;
  const int m = (bid >> 6) & 1;
  const int n = bid & 63;
  const int tid = threadIdx.x;
  const int b0 = m * 128;
  const int ncol = n * 16;
  const float* wt   = d ? wt_b : wt_f;
  const float* bias = d ? bias_b : bias_f;

  // --- W slice -> LDS, XOR-swizzled along k ---
  {
    const char* wsrc = (const char*)(w2t + ((size_t)d * G_ + n*64) * H_);
#pragma unroll
    for (int i = 0; i < 32; i++){
      int u = i*256 + tid;              // 8192 x 16B = 128KB
      int row = u >> 7, seg = u & 127;
      int sb = seg * 16;
      uint4 v = *(const uint4*)(wsrc + row*2048 + sb);
      *(uint4*)(smem + row*2048 + (sb ^ ((row & 7) << 4))) = v;
    }
  }

  const int w  = tid >> 6;   // wave 0..3, rows w*32..w*32+31
  const int l  = tid & 63;
  const int c  = l & 15;     // frag col = hidden col offset
  const int lk = l >> 4;     // k-seg
  const int gc = ncol + c;

  // --- per-lane constants ---
  float xav[3][4];
#pragma unroll
  for (int a = 0; a < 3; a++)
#pragma unroll
    for (int st = 0; st < 4; st++)
      xav[a][st] = wt[(size_t)(NI_ + a) * G_ + st*1024 + gc] + bias[st*1024 + gc];

  int len_r[8];
#pragma unroll
  for (int i = 0; i < 8; i++)
    len_r[i] = lens[b0 + w*32 + (i>>2)*16 + lk*4 + (i&3)];

  int it_c[8], ac_c[8];
  const int t0 = d ? (T_-1) : 0;
#pragma unroll
  for (int i = 0; i < 8; i++){
    int row = b0 + w*32 + (i>>2)*16 + lk*4 + (i&3);
    it_c[i] = items[(size_t)row * T_ + t0];
    ac_c[i] = actions[(size_t)row * T_ + t0];
  }

  // LDS b-read offset pieces: off = (st*16+c)*2048 + ((kk*64 + lk*16) ^ ((c&7)<<4))
  const int key  = (c & 7) << 4;
  const int kbit = (c >> 2) & 1;
  const u32 qoff00 = (u32)(c*2048 + ((lk*16) ^ (key & 48)));
  const u32 qd0 = (u32)((kbit) << 6);
  const u32 qd1 = (u32)((1 ^ kbit) << 6);

  float c_reg[8]; uint16_t h_reg[8];
#pragma unroll
  for (int i = 0; i < 8; i++){ c_reg[i] = 0.f; h_reg[i] = 0; }

  __syncthreads();   // W LDS ready (block-local)

  bf16x8 pre0[16], pre1[16];

  for (int s = 0; s < T_; s++){
    const int t = d ? (T_-1-s) : s;

    // --- acc init: x = Wt[item] + (Wt[NI+act] + bias), f32 gather (normal cached loads) ---
    f32x4 acc0[4], acc1[4];
#pragma unroll
    for (int r4 = 0; r4 < 4; r4++){
      const float* w0r = wt + (size_t)it_c[r4]   * G_ + gc;
      const float* w1r = wt + (size_t)it_c[4+r4] * G_ + gc;
#pragma unroll
      for (int st = 0; st < 4; st++){
        acc0[st][r4] = w0r[st*1024] + xav[ac_c[r4]][st];
        acc1[st][r4] = w1r[st*1024] + xav[ac_c[4+r4]][st];
      }
    }
    __builtin_amdgcn_sched_barrier(0);   // keep compiler vmem + its waits above the asm pipeline

    const uint16_t* hin  = hbuf + ((size_t)((s&1)*2 + d)) * B_ * H_;
    uint16_t*       hout = hbuf + ((size_t)(((s&1)^1)*2 + d)) * B_ * H_;
    const char* p0 = (const char*)hin + (size_t)(b0 + w*32 + c)*2048 + lk*16;
    const char* p1 = p0 + 16*2048;

    // --- prologue: issue 16 pairs of coherent A loads ---
    R16(AISS, 0)
    // --- k-loop: 32 fully-unrolled iterations ---
    R16(KSTEP, 0)
    R16(KSTEP, 16)
    __builtin_amdgcn_sched_barrier(0);

    // --- epilogue: gates in registers, c in registers, coherent h stores ---
    int tn = d ? (t > 0 ? t-1 : 0) : (t < T_-1 ? t+1 : t);
#pragma unroll
    for (int mi = 0; mi < 2; mi++)
#pragma unroll
      for (int r4 = 0; r4 < 4; r4++){
        int i8 = mi*4 + r4;
        int row = b0 + w*32 + mi*16 + lk*4 + r4;
        float g0 = mi ? acc1[0][r4] : acc0[0][r4];
        float g1 = mi ? acc1[1][r4] : acc0[1][r4];
        float g2 = mi ? acc1[2][r4] : acc0[2][r4];
        float g3 = mi ? acc1[3][r4] : acc0[3][r4];
        if (t < len_r[i8]){
          float i_ = sigm(g0);
          float f_ = sigm(g1);
          float gg = tanh_(g2);
          float o_ = sigm(g3);
          float cn = f_ * c_reg[i8] + i_ * gg;
          c_reg[i8] = cn;
          h_reg[i8] = f2bf(o_ * tanh_(cn));
        }
        const uint16_t* addr = hout + (size_t)row * H_ + gc;
        u32 hv = h_reg[i8];
        asm volatile("global_store_short %0, %1, off sc0 sc1" :: "v"(addr), "v"(hv) : "memory");
      }
    asm volatile("s_waitcnt vmcnt(0)" ::: "memory");
    __syncthreads();
    if (s == T_-1) break;

    // --- lightweight global barrier: release-adds (writeback, no invalidate) + relaxed polls ---
    u32* arr = bar + ((u32)s*8 + (u32)(bid & 7))*16;
    u32* fin = bar + 32768 + (u32)s*16;
    if (tid == 0){
      u32 old = __hip_atomic_fetch_add(arr, 1u, __ATOMIC_RELEASE, __HIP_MEMORY_SCOPE_AGENT);
      if (old == 31u)
        __hip_atomic_fetch_add(fin, 1u, __ATOMIC_RELEASE, __HIP_MEMORY_SCOPE_AGENT);
    }
    // prefetch next step's item/action while waiting
#pragma unroll
    for (int i = 0; i < 8; i++){
      int row = b0 + w*32 + (i>>2)*16 + lk*4 + (i&3);
      it_c[i] = items[(size_t)row * T_ + tn];
      ac_c[i] = actions[(size_t)row * T_ + tn];
    }
    if (tid == 0){
      while (__hip_atomic_load(fin, __ATOMIC_RELAXED, __HIP_MEMORY_SCOPE_AGENT) < 8u)
        __builtin_amdgcn_s_sleep(2);
    }
    __syncthreads();
  }
}

// ---- FC + per-row loss ----
__global__ __launch_bounds__(256) void k_fc(const uint16_t* __restrict__ hfin,
    const float* __restrict__ wfc, const float* __restrict__ bfc,
    const int* __restrict__ targets, float* __restrict__ rowloss){
  int b = blockIdx.x, tid = threadIdx.x;
  float a0 = 0.f, a1 = 0.f;
  for (int jj = tid; jj < 2*H_; jj += 256){
    int d = jj >> 10, j = jj & 1023;
    float h = bf2f(hfin[(size_t)d * B_ * H_ + (size_t)b * H_ + j]);
    u32 idx = (u32)(d * (B_ * H_) + b * H_ + j);
    float feat = keep_mask(idx) ? (2.f * h) : 0.f;
    a0 += feat * wfc[jj*2 + 0];
    a1 += feat * wfc[jj*2 + 1];
  }
#pragma unroll
  for (int off = 32; off > 0; off >>= 1){
    a0 += __shfl_down(a0, off, 64);
    a1 += __shfl_down(a1, off, 64);
  }
  __shared__ float r0[4], r1[4];
  if ((tid & 63) == 0){ r0[tid >> 6] = a0; r1[tid >> 6] = a1; }
  __syncthreads();
  if (tid == 0){
    float l0 = r0[0]+r0[1]+r0[2]+r0[3] + bfc[0];
    float l1 = r1[0]+r1[1]+r1[2]+r1[3] + bfc[1];
    float mx = fmaxf(l0, l1);
    float lse = mx + logf(__expf(l0 - mx) + __expf(l1 - mx));
    rowloss[b] = lse - (targets[b] ? l1 : l0);
  }
}

__global__ __launch_bounds__(256) void k_loss(const float* __restrict__ rowloss, float* __restrict__ out){
  int tid = threadIdx.x;
  float v = rowloss[tid];
#pragma unroll
  for (int off = 32; off > 0; off >>= 1) v += __shfl_down(v, off, 64);
  __shared__ float r[4];
  if ((tid & 63) == 0) r[tid >> 6] = v;
  __syncthreads();
  if (tid == 0) out[0] = (r[0] + r[1] + r[2] + r[3]) * (1.f / B_);
}

extern "C" void kernel_launch(void* const* d_in, const int* in_sizes, int n_in,
                              void* d_out, int out_size, void* d_ws, size_t ws_size,
                              hipStream_t stream){
  (void)in_sizes; (void)n_in; (void)out_size; (void)ws_size;
  const int*   items   = (const int*)  d_in[0];
  const int*   actions = (const int*)  d_in[1];
  const int*   targets = (const int*)  d_in[2];
  const float* wt_f    = (const float*)d_in[3];
  const float* whh_f   = (const float*)d_in[4];
  const float* b_f     = (const float*)d_in[5];
  const float* wt_b    = (const float*)d_in[6];
  const float* whh_b   = (const float*)d_in[7];
  const float* b_b     = (const float*)d_in[8];
  const float* wfc     = (const float*)d_in[9];
  const float* bfc     = (const float*)d_in[10];

  char* ws = (char*)d_ws;
  uint16_t* w2t   = (uint16_t*)(ws + OFF_W2T);
  uint16_t* hbuf  = (uint16_t*)(ws + OFF_H);
  int*      lens  = (int*)     (ws + OFF_LENS);
  float*    rlbuf = (float*)   (ws + OFF_RL);
  u32*      bar   = (u32*)     (ws + OFF_BAR);

  hipFuncSetAttribute((const void*)k_persist,
                      hipFuncAttributeMaxDynamicSharedMemorySize, LDS_BYTES);

  hipLaunchKernelGGL(k_prep_w, dim3(8192), dim3(256), 0, stream, whh_f, whh_b, w2t);
  hipLaunchKernelGGL(k_init,   dim3(257),  dim3(256), 0, stream, hbuf, lens, bar, items);

  void* args[] = { (void*)&items, (void*)&actions, (void*)&wt_f, (void*)&wt_b,
                   (void*)&b_f, (void*)&b_b, (void*)&w2t, (void*)&hbuf,
                   (void*)&lens, (void*)&bar };
  hipLaunchCooperativeKernel((const void*)k_persist, dim3(256), dim3(256),
                             args, LDS_BYTES, stream);

  hipLaunchKernelGGL(k_fc,   dim3(256), dim3(256), 0, stream, hbuf, wfc, bfc, targets, rlbuf);
  hipLaunchKernelGGL(k_loss, dim3(1),   dim3(256), 0, stream, rlbuf, (float*)d_out);
}